// Round 11
// baseline (100.482 us; speedup 1.0000x reference)
//
#include <hip/hip_runtime.h>

// Problem constants
#define T_LEN 4096
#define N_WIN 3969          // T - L + 1
#define K_SH  128
#define L_SH  128
#define B_SZ  256

#define SSTR  136           // S row stride (bf16 elems), 272 B
// x copy stride (bf16): 8720 B; stride/4 ≡ 4 (mod 32) -> 8 copy bases on
// distinct banks; padded so last-tile + boundary reads stay in range.
#define XSTR  4360

#define NEG_INF (-3.402823466e38f)

typedef __attribute__((ext_vector_type(8))) __bf16 bf16x8;
typedef __attribute__((ext_vector_type(16))) float f32x16;
typedef _Float16 h2 __attribute__((ext_vector_type(2)));   // packed half pair

__device__ __forceinline__ unsigned short f2bf(float f) {
    union { float f; unsigned int u; } c; c.f = f;
    unsigned int u = c.u + 0x7fff + ((c.u >> 16) & 1u);
    return (unsigned short)(u >> 16);
}
__device__ __forceinline__ unsigned int pack2(unsigned short lo, unsigned short hi) {
    return (unsigned int)lo | ((unsigned int)hi << 16);
}

// ---- packed-f16 selection primitives ----
__device__ __forceinline__ h2 max2(h2 a, h2 b) { return __builtin_elementwise_max(a, b); }
__device__ __forceinline__ h2 min2(h2 a, h2 b) { return __builtin_elementwise_min(a, b); }
__device__ __forceinline__ h2 cvt2(float lo, float hi) {
    return __builtin_bit_cast(h2, __builtin_amdgcn_cvt_pkrtz(lo, hi));
}
__device__ __forceinline__ void ce2(h2& hi, h2& lo) {
    const h2 m = max2(hi, lo);
    lo = min2(hi, lo);
    hi = m;
}
__device__ __forceinline__ void sort4_2(h2& a, h2& b, h2& c, h2& d) {
    ce2(a, b); ce2(c, d); ce2(a, c); ce2(b, d); ce2(b, c);
}
__device__ __forceinline__ void merge44_top5_2(h2 a0, h2 a1, h2 a2, h2 a3,
                                               h2 b0, h2 b1, h2 b2, h2 b3,
                                               h2& r0, h2& r1, h2& r2, h2& r3, h2& r4) {
    ce2(a0, b0); ce2(a2, b2); ce2(b0, a2);
    ce2(a1, b1); ce2(a3, b3); ce2(b1, a3);
    r0 = a0;
    r1 = a1; r2 = b0; ce2(r1, r2);
    r3 = b1; r4 = a2; ce2(r3, r4);
}
// r = top-5 of union of two descending sorted 5-lists (c_k = max_{i+j=k} min(a_i,b_j))
__device__ __forceinline__ void merge55_2(h2& r0, h2& r1, h2& r2, h2& r3, h2& r4,
                                          h2 s0, h2 s1, h2 s2, h2 s3, h2 s4) {
    const h2 m00 = min2(r0, s0);
    const h2 m10 = min2(r1, s0), m01 = min2(r0, s1);
    const h2 m20 = min2(r2, s0), m11 = min2(r1, s1), m02 = min2(r0, s2);
    const h2 m30 = min2(r3, s0), m21 = min2(r2, s1), m12 = min2(r1, s2), m03 = min2(r0, s3);
    const h2 n0 = max2(r0, s0);
    const h2 n1 = max2(max2(r1, s1), m00);
    const h2 n2 = max2(max2(r2, s2), max2(m10, m01));
    const h2 n3 = max2(max2(max2(r3, s3), m20), max2(m11, m02));
    const h2 n4 = max2(max2(max2(r4, s4), max2(m30, m03)), max2(m21, m12));
    r0 = n0; r1 = n1; r2 = n2; r3 = n3; r4 = n4;
}
// ---- scalar f32 helpers (epilogue only) ----
__device__ __forceinline__ void merge55f(float& r0, float& r1, float& r2, float& r3, float& r4,
                                         float s0, float s1, float s2, float s3, float s4) {
    const float m00 = fminf(r0, s0);
    const float m10 = fminf(r1, s0), m01 = fminf(r0, s1);
    const float m20 = fminf(r2, s0), m11 = fminf(r1, s1), m02 = fminf(r0, s2);
    const float m30 = fminf(r3, s0), m21 = fminf(r2, s1), m12 = fminf(r1, s2), m03 = fminf(r0, s3);
    const float n0 = fmaxf(r0, s0);
    const float n1 = fmaxf(fmaxf(r1, s1), m00);
    const float n2 = fmaxf(fmaxf(r2, s2), fmaxf(m10, m01));
    const float n3 = fmaxf(fmaxf(fmaxf(r3, s3), m20), fmaxf(m11, m02));
    const float n4 = fmaxf(fmaxf(fmaxf(r4, s4), fmaxf(m30, m03)), fmaxf(m21, m12));
    r0 = n0; r1 = n1; r2 = n2; r3 = n3; r4 = n4;
}
__device__ __forceinline__ void top5_insertf(float v, float& t0, float& t1,
                                             float& t2, float& t3, float& t4) {
    float b = fmaxf(t4, v);
    float m;
    m = fmaxf(t3, b);  b  = fminf(t3, b);  t3 = m;
    m = fmaxf(t2, t3); t3 = fminf(t2, t3); t2 = m;
    m = fmaxf(t1, t2); t2 = fminf(t1, t2); t1 = m;
    m = fmaxf(t0, t1); t1 = fminf(t0, t1); t0 = m;
    t4 = b;
}
// fold 32 acc values (two 32x32 accs, SAME column per lane: elem0 = mt-even
// rows, elem1 = mt-odd rows) into the packed running top-5
__device__ __forceinline__ void select32b(const f32x16& A0, const f32x16& A1, h2* rt) {
    h2 p[16];
    #pragma unroll
    for (int i = 0; i < 16; ++i) p[i] = cvt2(A0[i], A1[i]);
    sort4_2(p[0],  p[1],  p[2],  p[3]);
    sort4_2(p[4],  p[5],  p[6],  p[7]);
    sort4_2(p[8],  p[9],  p[10], p[11]);
    sort4_2(p[12], p[13], p[14], p[15]);
    h2 u0, u1, u2, u3, u4, v0, v1, v2, v3, v4;
    merge44_top5_2(p[0], p[1], p[2],  p[3],  p[4],  p[5],  p[6],  p[7],  u0, u1, u2, u3, u4);
    merge44_top5_2(p[8], p[9], p[10], p[11], p[12], p[13], p[14], p[15], v0, v1, v2, v3, v4);
    merge55_2(u0, u1, u2, u3, u4, v0, v1, v2, v3, v4);
    merge55_2(rt[0], rt[1], rt[2], rt[3], rt[4], u0, u1, u2, u3, u4);
}

// Single fused kernel: grid = B (256 blocks, 1/CU), 1024 threads (16 waves).
// 32x32x16 MFMA. Wave w: g = w>>3 tile parity; mp = (w>>2)&1 mt-pair
// (rows 64*mp + [0,64) of each 128-tile); kt = w&3 (cols 32*kt + [0,32)).
// A-layout: lane m = lane&31, k = 8*(lane>>5)+j -> Hankel frag = one b128
// from shifted copy c7 = lane&7. C-layout (m74/m101): col = lane&31,
// row = (reg&3) + 8*(reg>>2) + 4*(lane>>5) -> one column per lane.
__global__ __launch_bounds__(1024)
void shapelet_fused_kernel(const float* __restrict__ x,
                           const float* __restrict__ s,
                           float* __restrict__ out) {
    __shared__ __align__(16) unsigned short ldsS[K_SH * SSTR];   // 34816 B
    __shared__ __align__(16) unsigned short ldsX[8 * XSTR];      // 69760 B

    const int t    = threadIdx.x;
    const int lane = t & 63;
    const int w    = t >> 6;
    const int c7   = lane & 7;
    const int ub2  = (lane >> 3) & 3;
    const int q2   = lane >> 5;
    const int col  = lane & 31;
    const int g    = w >> 3;
    const int mp   = (w >> 2) & 1;
    const int kt   = w & 3;
    const int b    = blockIdx.x;

    // ---- stage centered S as bf16: 8 threads per row k, 16 elems each ----
    {
        const int k = t >> 3, e8 = t & 7;
        const float4* srow = (const float4*)(s + k * L_SH + e8 * 16);
        float4 v[4];
        float sum = 0.0f;
        #pragma unroll
        for (int j = 0; j < 4; ++j) {
            v[j] = srow[j];
            sum += (v[j].x + v[j].y) + (v[j].z + v[j].w);
        }
        sum += __shfl_xor(sum, 1);
        sum += __shfl_xor(sum, 2);
        sum += __shfl_xor(sum, 4);
        const float mean = sum * (1.0f / 128.0f);
        uint4* dst = (uint4*)((char*)ldsS + k * (SSTR * 2) + e8 * 32);
        #pragma unroll
        for (int j = 0; j < 2; ++j) {
            uint4 o;
            o.x = pack2(f2bf(v[2*j].x - mean),   f2bf(v[2*j].y - mean));
            o.y = pack2(f2bf(v[2*j].z - mean),   f2bf(v[2*j].w - mean));
            o.z = pack2(f2bf(v[2*j+1].x - mean), f2bf(v[2*j+1].y - mean));
            o.w = pack2(f2bf(v[2*j+1].z - mean), f2bf(v[2*j+1].w - mean));
            dst[j] = o;
        }
        if (e8 == 7) *(uint4*)((char*)ldsS + k * (SSTR * 2) + 256) = make_uint4(0,0,0,0);
    }

    // ---- stage x row as 8 shifted bf16 copies; thread -> (copy = t&7, chunk) ----
    {
        const float* __restrict__ xb = x + (size_t)b * T_LEN;
        const int a = t & 7;
        for (int i = (t >> 3); i < XSTR / 8; i += 128) {
            const int p0 = 8 * i;
            float xv[16];
            if (p0 + 16 <= T_LEN) {
                const float4* sp = (const float4*)(xb + p0);
                #pragma unroll
                for (int j = 0; j < 4; ++j) *(float4*)(xv + 4 * j) = sp[j];
            } else {
                #pragma unroll
                for (int j = 0; j < 16; ++j) {
                    const int gi = p0 + j;
                    xv[j] = (gi < T_LEN) ? xb[gi] : 0.0f;
                }
            }
            unsigned short bv[16];
            #pragma unroll
            for (int j = 0; j < 16; ++j) bv[j] = f2bf(xv[j]);
            uint4 o;
            o.x = pack2(bv[a],     bv[a + 1]);
            o.y = pack2(bv[a + 2], bv[a + 3]);
            o.z = pack2(bv[a + 4], bv[a + 5]);
            o.w = pack2(bv[a + 6], bv[a + 7]);
            *(uint4*)((char*)ldsX + a * (XSTR * 2) + 2 * p0) = o;
        }
    }
    __syncthreads();

    // ---- hoist B fragments: wave's kt, 8 K-chunks of 16 ----
    // B[k][col]: k = 16*c + 8*q2 + j, shapelet ks = 32*kt + col.
    bf16x8 bfr[8];
    #pragma unroll
    for (int c = 0; c < 8; ++c)
        bfr[c] = __builtin_bit_cast(bf16x8, *(const uint4*)(
            (const char*)ldsS + (32 * kt + col) * (SSTR * 2) + 32 * c + 16 * q2));

    // packed running top-5 (one column per lane; elem0 = mt 2mp rows, elem1 = mt 2mp+1)
    h2 rt[5];
    #pragma unroll
    for (int i = 0; i < 5; ++i) rt[i] = __builtin_bit_cast(h2, 0xFC00FC00u);

    // A-frag pointer: frag u at xp + 32*u; u = 2*(mt-2mp) + c in [0,10)
    const char* xp = (const char*)ldsX + c7 * (XSTR * 2) + 16 * ub2 + 16 * q2
                   + 128 * mp + g * 256;

    f32x16 aA0, aA1, aB0, aB1;

#define LD(U) __builtin_bit_cast(bf16x8, *(const uint4*)(xp + 32 * (U)))
#define COMPUTE(X0, X1)                                                         \
    {                                                                           \
        _Pragma("unroll")                                                       \
        for (int i = 0; i < 16; ++i) { X0[i] = 0.f; X1[i] = 0.f; }              \
        bf16x8 f;                                                               \
        f = LD(0); X0 = __builtin_amdgcn_mfma_f32_32x32x16_bf16(f, bfr[0], X0, 0, 0, 0); \
        f = LD(1); X0 = __builtin_amdgcn_mfma_f32_32x32x16_bf16(f, bfr[1], X0, 0, 0, 0); \
        f = LD(2); X0 = __builtin_amdgcn_mfma_f32_32x32x16_bf16(f, bfr[2], X0, 0, 0, 0); \
                   X1 = __builtin_amdgcn_mfma_f32_32x32x16_bf16(f, bfr[0], X1, 0, 0, 0); \
        f = LD(3); X0 = __builtin_amdgcn_mfma_f32_32x32x16_bf16(f, bfr[3], X0, 0, 0, 0); \
                   X1 = __builtin_amdgcn_mfma_f32_32x32x16_bf16(f, bfr[1], X1, 0, 0, 0); \
        f = LD(4); X0 = __builtin_amdgcn_mfma_f32_32x32x16_bf16(f, bfr[4], X0, 0, 0, 0); \
                   X1 = __builtin_amdgcn_mfma_f32_32x32x16_bf16(f, bfr[2], X1, 0, 0, 0); \
        f = LD(5); X0 = __builtin_amdgcn_mfma_f32_32x32x16_bf16(f, bfr[5], X0, 0, 0, 0); \
                   X1 = __builtin_amdgcn_mfma_f32_32x32x16_bf16(f, bfr[3], X1, 0, 0, 0); \
        f = LD(6); X0 = __builtin_amdgcn_mfma_f32_32x32x16_bf16(f, bfr[6], X0, 0, 0, 0); \
                   X1 = __builtin_amdgcn_mfma_f32_32x32x16_bf16(f, bfr[4], X1, 0, 0, 0); \
        f = LD(7); X0 = __builtin_amdgcn_mfma_f32_32x32x16_bf16(f, bfr[7], X0, 0, 0, 0); \
                   X1 = __builtin_amdgcn_mfma_f32_32x32x16_bf16(f, bfr[5], X1, 0, 0, 0); \
        f = LD(8); X1 = __builtin_amdgcn_mfma_f32_32x32x16_bf16(f, bfr[6], X1, 0, 0, 0); \
        f = LD(9); X1 = __builtin_amdgcn_mfma_f32_32x32x16_bf16(f, bfr[7], X1, 0, 0, 0); \
        xp += 512;                                                              \
    }

    // pipeline: COMPUTE(tile i+1) issued before SELECT(tile i) -> the VALU
    // network runs while tile i+1's MFMAs drain through the matrix pipe.
    COMPUTE(aA0, aA1)
    for (int st = 0; st < 7; ++st) {
        COMPUTE(aB0, aB1) select32b(aA0, aA1, rt);
        COMPUTE(aA0, aA1) select32b(aB0, aB1, rt);
    }
    if (g == 0) {
        COMPUTE(aB0, aB1) select32b(aA0, aA1, rt);
        select32b(aB0, aB1, rt);
    } else {
        select32b(aA0, aA1, rt);
    }
#undef COMPUTE
#undef LD

    // ---- boundary row n = 3968 (element byte offset 7936), by (g=1, mp=0) ----
    f32x16 eb;
    if (g == 1 && mp == 0) {
        #pragma unroll
        for (int i = 0; i < 16; ++i) eb[i] = 0.f;
        const char* ebase = (const char*)ldsX + c7 * (XSTR * 2) + 16 * ub2 + 16 * q2 + 7936;
        #pragma unroll
        for (int c = 0; c < 8; ++c) {
            const bf16x8 f = __builtin_bit_cast(bf16x8, *(const uint4*)(ebase + 32 * c));
            eb = __builtin_amdgcn_mfma_f32_32x32x16_bf16(f, bfr[c], eb, 0, 0, 0);
        }
    }

    // ---- epilogue: unpack both row-groups of the column list and merge ----
    float a0 = (float)rt[0][0], a1 = (float)rt[1][0], a2 = (float)rt[2][0],
          a3 = (float)rt[3][0], a4 = (float)rt[4][0];
    merge55f(a0, a1, a2, a3, a4,
             (float)rt[0][1], (float)rt[1][1], (float)rt[2][1],
             (float)rt[3][1], (float)rt[4][1]);

    // boundary insert: eb reg0 row = 4*q2 -> n=3968 valid only for q2==0 lanes
    if (g == 1 && mp == 0) {
        const float v = (q2 == 0) ? eb[0] : NEG_INF;
        top5_insertf(v, a0, a1, a2, a3, a4);
    }

    // merge the two q2 halves of each column (snapshot BEFORE merging)
    {
        const float s0 = __shfl_xor(a0, 32), s1 = __shfl_xor(a1, 32),
                    s2 = __shfl_xor(a2, 32), s3 = __shfl_xor(a3, 32),
                    s4 = __shfl_xor(a4, 32);
        merge55f(a0, a1, a2, a3, a4, s0, s1, s2, s3, s4);
    }

    // ---- cross-(g, mp) merge via LDS: slots 1..3 write, slot 0 reads ----
    __syncthreads();   // every wave past its bfr hoist & tile loop; ldsS reusable
    float* sc = (float*)ldsS;          // [slot-1][128 cols][5]
    const int slot = 2 * g + mp;
    if (slot != 0 && lane < 32) {
        float* p = sc + (((slot - 1) * 128) + kt * 32 + col) * 5;
        p[0] = a0; p[1] = a1; p[2] = a2; p[3] = a3; p[4] = a4;
    }
    __syncthreads();
    if (slot == 0 && lane < 32) {
        #pragma unroll
        for (int sreg = 0; sreg < 3; ++sreg) {
            const float* p = sc + ((sreg * 128) + kt * 32 + col) * 5;
            merge55f(a0, a1, a2, a3, a4, p[0], p[1], p[2], p[3], p[4]);
        }
        const int ks = 32 * kt + col;
        float* ob = out + (size_t)b * (4 * K_SH);
        const float pmean = (((a0 + a1) + (a2 + a3)) + a4) * 0.2f;
        ob[ks]            = a0;
        ob[K_SH + ks]     = pmean;
        ob[2*K_SH + ks]   = a1;
        ob[3*K_SH + ks]   = fmaxf(a0 - a1, 0.0f);
    }
}

extern "C" void kernel_launch(void* const* d_in, const int* in_sizes, int n_in,
                              void* d_out, int out_size, void* d_ws, size_t ws_size,
                              hipStream_t stream) {
    const float* x = (const float*)d_in[0];        // (256, 4096) fp32
    const float* s = (const float*)d_in[1];        // (128, 128)  fp32
    float* out = (float*)d_out;                    // (256, 512)  fp32
    shapelet_fused_kernel<<<B_SZ, 1024, 0, stream>>>(x, s, out);
}

// Round 12
// 96.121 us; speedup vs baseline: 1.0454x; 1.0454x over previous
//
#include <hip/hip_runtime.h>

// Problem constants
#define T_LEN 4096
#define N_WIN 3969          // T - L + 1
#define K_SH  128
#define L_SH  128
#define B_SZ  256

#define SSTR  136           // S row stride (bf16 elems), 272 B
// x copy stride (bf16): 8720 B; stride/4 ≡ 4 (mod 32) -> 8 copy bases on
// distinct banks; padded so last-tile + boundary reads stay in range.
#define XSTR  4360

#define NEG_INF (-3.402823466e38f)

typedef __attribute__((ext_vector_type(8))) __bf16 bf16x8;
typedef __attribute__((ext_vector_type(16))) float f32x16;
typedef _Float16 h2 __attribute__((ext_vector_type(2)));   // packed half pair

__device__ __forceinline__ unsigned short f2bf(float f) {
    union { float f; unsigned int u; } c; c.f = f;
    unsigned int u = c.u + 0x7fff + ((c.u >> 16) & 1u);
    return (unsigned short)(u >> 16);
}
__device__ __forceinline__ unsigned int pack2(unsigned short lo, unsigned short hi) {
    return (unsigned int)lo | ((unsigned int)hi << 16);
}

// ---- packed-f16 selection primitives ----
__device__ __forceinline__ h2 max2(h2 a, h2 b) { return __builtin_elementwise_max(a, b); }
__device__ __forceinline__ h2 min2(h2 a, h2 b) { return __builtin_elementwise_min(a, b); }
__device__ __forceinline__ h2 cvt2(float lo, float hi) {
    return __builtin_bit_cast(h2, __builtin_amdgcn_cvt_pkrtz(lo, hi));
}
__device__ __forceinline__ void ce2(h2& hi, h2& lo) {
    const h2 m = max2(hi, lo);
    lo = min2(hi, lo);
    hi = m;
}
__device__ __forceinline__ void sort4_2(h2& a, h2& b, h2& c, h2& d) {
    ce2(a, b); ce2(c, d); ce2(a, c); ce2(b, d); ce2(b, c);
}
__device__ __forceinline__ void merge44_top5_2(h2 a0, h2 a1, h2 a2, h2 a3,
                                               h2 b0, h2 b1, h2 b2, h2 b3,
                                               h2& r0, h2& r1, h2& r2, h2& r3, h2& r4) {
    ce2(a0, b0); ce2(a2, b2); ce2(b0, a2);
    ce2(a1, b1); ce2(a3, b3); ce2(b1, a3);
    r0 = a0;
    r1 = a1; r2 = b0; ce2(r1, r2);
    r3 = b1; r4 = a2; ce2(r3, r4);
}
// r = top-5 of union of two descending sorted 5-lists (c_k = max_{i+j=k} min(a_i,b_j))
__device__ __forceinline__ void merge55_2(h2& r0, h2& r1, h2& r2, h2& r3, h2& r4,
                                          h2 s0, h2 s1, h2 s2, h2 s3, h2 s4) {
    const h2 m00 = min2(r0, s0);
    const h2 m10 = min2(r1, s0), m01 = min2(r0, s1);
    const h2 m20 = min2(r2, s0), m11 = min2(r1, s1), m02 = min2(r0, s2);
    const h2 m30 = min2(r3, s0), m21 = min2(r2, s1), m12 = min2(r1, s2), m03 = min2(r0, s3);
    const h2 n0 = max2(r0, s0);
    const h2 n1 = max2(max2(r1, s1), m00);
    const h2 n2 = max2(max2(r2, s2), max2(m10, m01));
    const h2 n3 = max2(max2(max2(r3, s3), m20), max2(m11, m02));
    const h2 n4 = max2(max2(max2(r4, s4), max2(m30, m03)), max2(m21, m12));
    r0 = n0; r1 = n1; r2 = n2; r3 = n3; r4 = n4;
}
// ---- scalar f32 helpers (epilogue only) ----
__device__ __forceinline__ void merge55f(float& r0, float& r1, float& r2, float& r3, float& r4,
                                         float s0, float s1, float s2, float s3, float s4) {
    const float m00 = fminf(r0, s0);
    const float m10 = fminf(r1, s0), m01 = fminf(r0, s1);
    const float m20 = fminf(r2, s0), m11 = fminf(r1, s1), m02 = fminf(r0, s2);
    const float m30 = fminf(r3, s0), m21 = fminf(r2, s1), m12 = fminf(r1, s2), m03 = fminf(r0, s3);
    const float n0 = fmaxf(r0, s0);
    const float n1 = fmaxf(fmaxf(r1, s1), m00);
    const float n2 = fmaxf(fmaxf(r2, s2), fmaxf(m10, m01));
    const float n3 = fmaxf(fmaxf(fmaxf(r3, s3), m20), fmaxf(m11, m02));
    const float n4 = fmaxf(fmaxf(fmaxf(r4, s4), fmaxf(m30, m03)), fmaxf(m21, m12));
    r0 = n0; r1 = n1; r2 = n2; r3 = n3; r4 = n4;
}
__device__ __forceinline__ void top5_insertf(float v, float& t0, float& t1,
                                             float& t2, float& t3, float& t4) {
    float b = fmaxf(t4, v);
    float m;
    m = fmaxf(t3, b);  b  = fminf(t3, b);  t3 = m;
    m = fmaxf(t2, t3); t3 = fminf(t2, t3); t2 = m;
    m = fmaxf(t1, t2); t2 = fminf(t1, t2); t1 = m;
    m = fmaxf(t0, t1); t1 = fminf(t0, t1); t0 = m;
    t4 = b;
}
// fold 32 acc values (two 32x32 accs, SAME column per lane: elem0 = mt-even
// rows, elem1 = mt-odd rows) into the packed running top-5
__device__ __forceinline__ void select32b(const f32x16& A0, const f32x16& A1, h2* rt) {
    h2 p[16];
    #pragma unroll
    for (int i = 0; i < 16; ++i) p[i] = cvt2(A0[i], A1[i]);
    sort4_2(p[0],  p[1],  p[2],  p[3]);
    sort4_2(p[4],  p[5],  p[6],  p[7]);
    sort4_2(p[8],  p[9],  p[10], p[11]);
    sort4_2(p[12], p[13], p[14], p[15]);
    h2 u0, u1, u2, u3, u4, v0, v1, v2, v3, v4;
    merge44_top5_2(p[0], p[1], p[2],  p[3],  p[4],  p[5],  p[6],  p[7],  u0, u1, u2, u3, u4);
    merge44_top5_2(p[8], p[9], p[10], p[11], p[12], p[13], p[14], p[15], v0, v1, v2, v3, v4);
    merge55_2(u0, u1, u2, u3, u4, v0, v1, v2, v3, v4);
    merge55_2(rt[0], rt[1], rt[2], rt[3], rt[4], u0, u1, u2, u3, u4);
}

// Single fused kernel: grid = B (256 blocks, 1/CU), 1024 threads (16 waves).
// 32x32x16 MFMA, SINGLE acc pair (R11's double-buffer spilled: 64 acc regs +
// afr/select transients blew the 128-reg unified budget -> 26 MB scratch).
// Wave w: g = w>>3 tile parity; mp = (w>>2)&1 mt-pair; kt = w&3.
// C-layout (m74/m101): col = lane&31, row = (reg&3)+8*(reg>>2)+4*(lane>>5)
// -> each lane's 32 acc values belong to ONE shapelet column.
__global__ __launch_bounds__(1024)
void shapelet_fused_kernel(const float* __restrict__ x,
                           const float* __restrict__ s,
                           float* __restrict__ out) {
    __shared__ __align__(16) unsigned short ldsS[K_SH * SSTR];   // 34816 B
    __shared__ __align__(16) unsigned short ldsX[8 * XSTR];      // 69760 B

    const int t    = threadIdx.x;
    const int lane = t & 63;
    const int w    = t >> 6;
    const int c7   = lane & 7;
    const int ub2  = (lane >> 3) & 3;
    const int q2   = lane >> 5;
    const int col  = lane & 31;
    const int g    = w >> 3;
    const int mp   = (w >> 2) & 1;
    const int kt   = w & 3;
    const int b    = blockIdx.x;

    // ---- stage centered S as bf16: 8 threads per row k, 16 elems each ----
    {
        const int k = t >> 3, e8 = t & 7;
        const float4* srow = (const float4*)(s + k * L_SH + e8 * 16);
        float4 v[4];
        float sum = 0.0f;
        #pragma unroll
        for (int j = 0; j < 4; ++j) {
            v[j] = srow[j];
            sum += (v[j].x + v[j].y) + (v[j].z + v[j].w);
        }
        sum += __shfl_xor(sum, 1);
        sum += __shfl_xor(sum, 2);
        sum += __shfl_xor(sum, 4);
        const float mean = sum * (1.0f / 128.0f);
        uint4* dst = (uint4*)((char*)ldsS + k * (SSTR * 2) + e8 * 32);
        #pragma unroll
        for (int j = 0; j < 2; ++j) {
            uint4 o;
            o.x = pack2(f2bf(v[2*j].x - mean),   f2bf(v[2*j].y - mean));
            o.y = pack2(f2bf(v[2*j].z - mean),   f2bf(v[2*j].w - mean));
            o.z = pack2(f2bf(v[2*j+1].x - mean), f2bf(v[2*j+1].y - mean));
            o.w = pack2(f2bf(v[2*j+1].z - mean), f2bf(v[2*j+1].w - mean));
            dst[j] = o;
        }
        if (e8 == 7) *(uint4*)((char*)ldsS + k * (SSTR * 2) + 256) = make_uint4(0,0,0,0);
    }

    // ---- stage x row as 8 shifted bf16 copies; thread -> (copy = t&7, chunk) ----
    {
        const float* __restrict__ xb = x + (size_t)b * T_LEN;
        const int a = t & 7;
        for (int i = (t >> 3); i < XSTR / 8; i += 128) {
            const int p0 = 8 * i;
            float xv[16];
            if (p0 + 16 <= T_LEN) {
                const float4* sp = (const float4*)(xb + p0);
                #pragma unroll
                for (int j = 0; j < 4; ++j) *(float4*)(xv + 4 * j) = sp[j];
            } else {
                #pragma unroll
                for (int j = 0; j < 16; ++j) {
                    const int gi = p0 + j;
                    xv[j] = (gi < T_LEN) ? xb[gi] : 0.0f;
                }
            }
            unsigned short bv[16];
            #pragma unroll
            for (int j = 0; j < 16; ++j) bv[j] = f2bf(xv[j]);
            uint4 o;
            o.x = pack2(bv[a],     bv[a + 1]);
            o.y = pack2(bv[a + 2], bv[a + 3]);
            o.z = pack2(bv[a + 4], bv[a + 5]);
            o.w = pack2(bv[a + 6], bv[a + 7]);
            *(uint4*)((char*)ldsX + a * (XSTR * 2) + 2 * p0) = o;
        }
    }
    __syncthreads();

    // ---- hoist B fragments: wave's kt, 8 K-chunks of 16 ----
    bf16x8 bfr[8];
    #pragma unroll
    for (int c = 0; c < 8; ++c)
        bfr[c] = __builtin_bit_cast(bf16x8, *(const uint4*)(
            (const char*)ldsS + (32 * kt + col) * (SSTR * 2) + 32 * c + 16 * q2));

    // packed running top-5 (one column per lane; elem0 = mt 2mp rows, elem1 = mt 2mp+1)
    h2 rt[5];
    #pragma unroll
    for (int i = 0; i < 5; ++i) rt[i] = __builtin_bit_cast(h2, 0xFC00FC00u);

    // A-frag pointer: frag u at xp + 32*u; u = 2*(mt-2mp) + c in [0,10)
    const char* xp = (const char*)ldsX + c7 * (XSTR * 2) + 16 * ub2 + 16 * q2
                   + 128 * mp + g * 256;

    f32x16 aA0, aA1;

#define LD(U) __builtin_bit_cast(bf16x8, *(const uint4*)(xp + 32 * (U)))
#define COMPUTE(X0, X1)                                                         \
    {                                                                           \
        _Pragma("unroll")                                                       \
        for (int i = 0; i < 16; ++i) { X0[i] = 0.f; X1[i] = 0.f; }              \
        bf16x8 f;                                                               \
        f = LD(0); X0 = __builtin_amdgcn_mfma_f32_32x32x16_bf16(f, bfr[0], X0, 0, 0, 0); \
        f = LD(1); X0 = __builtin_amdgcn_mfma_f32_32x32x16_bf16(f, bfr[1], X0, 0, 0, 0); \
        f = LD(2); X0 = __builtin_amdgcn_mfma_f32_32x32x16_bf16(f, bfr[2], X0, 0, 0, 0); \
                   X1 = __builtin_amdgcn_mfma_f32_32x32x16_bf16(f, bfr[0], X1, 0, 0, 0); \
        f = LD(3); X0 = __builtin_amdgcn_mfma_f32_32x32x16_bf16(f, bfr[3], X0, 0, 0, 0); \
                   X1 = __builtin_amdgcn_mfma_f32_32x32x16_bf16(f, bfr[1], X1, 0, 0, 0); \
        f = LD(4); X0 = __builtin_amdgcn_mfma_f32_32x32x16_bf16(f, bfr[4], X0, 0, 0, 0); \
                   X1 = __builtin_amdgcn_mfma_f32_32x32x16_bf16(f, bfr[2], X1, 0, 0, 0); \
        f = LD(5); X0 = __builtin_amdgcn_mfma_f32_32x32x16_bf16(f, bfr[5], X0, 0, 0, 0); \
                   X1 = __builtin_amdgcn_mfma_f32_32x32x16_bf16(f, bfr[3], X1, 0, 0, 0); \
        f = LD(6); X0 = __builtin_amdgcn_mfma_f32_32x32x16_bf16(f, bfr[6], X0, 0, 0, 0); \
                   X1 = __builtin_amdgcn_mfma_f32_32x32x16_bf16(f, bfr[4], X1, 0, 0, 0); \
        f = LD(7); X0 = __builtin_amdgcn_mfma_f32_32x32x16_bf16(f, bfr[7], X0, 0, 0, 0); \
                   X1 = __builtin_amdgcn_mfma_f32_32x32x16_bf16(f, bfr[5], X1, 0, 0, 0); \
        f = LD(8); X1 = __builtin_amdgcn_mfma_f32_32x32x16_bf16(f, bfr[6], X1, 0, 0, 0); \
        f = LD(9); X1 = __builtin_amdgcn_mfma_f32_32x32x16_bf16(f, bfr[7], X1, 0, 0, 0); \
        xp += 512;                                                              \
    }

    // g=0 waves: tiles 0,2,...,30 (16 steps); g=1: tiles 1,3,...,29 (15 steps)
    for (int st = 0; st < 15; ++st) {
        COMPUTE(aA0, aA1)
        select32b(aA0, aA1, rt);
    }
    if (g == 0) {
        COMPUTE(aA0, aA1)
        select32b(aA0, aA1, rt);
    }
#undef COMPUTE
#undef LD

    // ---- boundary row n = 3968 (element byte offset 7936), by (g=1, mp=0) ----
    f32x16 eb;
    if (g == 1 && mp == 0) {
        #pragma unroll
        for (int i = 0; i < 16; ++i) eb[i] = 0.f;
        const char* ebase = (const char*)ldsX + c7 * (XSTR * 2) + 16 * ub2 + 16 * q2 + 7936;
        #pragma unroll
        for (int c = 0; c < 8; ++c) {
            const bf16x8 f = __builtin_bit_cast(bf16x8, *(const uint4*)(ebase + 32 * c));
            eb = __builtin_amdgcn_mfma_f32_32x32x16_bf16(f, bfr[c], eb, 0, 0, 0);
        }
    }

    // ---- epilogue: unpack both row-groups of the column list and merge ----
    float a0 = (float)rt[0][0], a1 = (float)rt[1][0], a2 = (float)rt[2][0],
          a3 = (float)rt[3][0], a4 = (float)rt[4][0];
    merge55f(a0, a1, a2, a3, a4,
             (float)rt[0][1], (float)rt[1][1], (float)rt[2][1],
             (float)rt[3][1], (float)rt[4][1]);

    // boundary insert: eb reg0 row = 4*q2 -> n=3968 valid only for q2==0 lanes
    if (g == 1 && mp == 0) {
        const float v = (q2 == 0) ? eb[0] : NEG_INF;
        top5_insertf(v, a0, a1, a2, a3, a4);
    }

    // merge the two q2 halves of each column (snapshot BEFORE merging)
    {
        const float s0 = __shfl_xor(a0, 32), s1 = __shfl_xor(a1, 32),
                    s2 = __shfl_xor(a2, 32), s3 = __shfl_xor(a3, 32),
                    s4 = __shfl_xor(a4, 32);
        merge55f(a0, a1, a2, a3, a4, s0, s1, s2, s3, s4);
    }

    // ---- cross-(g, mp) merge via LDS: slots 1..3 write, slot 0 reads ----
    __syncthreads();   // every wave past its bfr hoist & tile loop; ldsS reusable
    float* sc = (float*)ldsS;          // [slot-1][128 cols][5]
    const int slot = 2 * g + mp;
    if (slot != 0 && lane < 32) {
        float* p = sc + (((slot - 1) * 128) + kt * 32 + col) * 5;
        p[0] = a0; p[1] = a1; p[2] = a2; p[3] = a3; p[4] = a4;
    }
    __syncthreads();
    if (slot == 0 && lane < 32) {
        #pragma unroll
        for (int sreg = 0; sreg < 3; ++sreg) {
            const float* p = sc + ((sreg * 128) + kt * 32 + col) * 5;
            merge55f(a0, a1, a2, a3, a4, p[0], p[1], p[2], p[3], p[4]);
        }
        const int ks = 32 * kt + col;
        float* ob = out + (size_t)b * (4 * K_SH);
        const float pmean = (((a0 + a1) + (a2 + a3)) + a4) * 0.2f;
        ob[ks]            = a0;
        ob[K_SH + ks]     = pmean;
        ob[2*K_SH + ks]   = a1;
        ob[3*K_SH + ks]   = fmaxf(a0 - a1, 0.0f);
    }
}

extern "C" void kernel_launch(void* const* d_in, const int* in_sizes, int n_in,
                              void* d_out, int out_size, void* d_ws, size_t ws_size,
                              hipStream_t stream) {
    const float* x = (const float*)d_in[0];        // (256, 4096) fp32
    const float* s = (const float*)d_in[1];        // (128, 128)  fp32
    float* out = (float*)d_out;                    // (256, 512)  fp32
    shapelet_fused_kernel<<<B_SZ, 1024, 0, stream>>>(x, s, out);
}

// Round 13
// 94.904 us; speedup vs baseline: 1.0588x; 1.0128x over previous
//
#include <hip/hip_runtime.h>

// Problem constants
#define T_LEN 4096
#define N_WIN 3969          // T - L + 1
#define K_SH  128
#define L_SH  128
#define B_SZ  256

#define SSTR  136           // S row stride (bf16 elems), 272 B
// x copy stride (bf16): 8720 B; stride/4 ≡ 4 (mod 32) -> 8 copy bases on
// distinct banks; padded so last-tile + boundary reads stay in range.
#define XSTR  4360

#define NEG_INF (-3.402823466e38f)

typedef __attribute__((ext_vector_type(8))) __bf16 bf16x8;
typedef __attribute__((ext_vector_type(16))) float f32x16;
typedef _Float16 h2 __attribute__((ext_vector_type(2)));   // packed half pair

__device__ __forceinline__ unsigned short f2bf(float f) {
    union { float f; unsigned int u; } c; c.f = f;
    unsigned int u = c.u + 0x7fff + ((c.u >> 16) & 1u);
    return (unsigned short)(u >> 16);
}
__device__ __forceinline__ unsigned int pack2(unsigned short lo, unsigned short hi) {
    return (unsigned int)lo | ((unsigned int)hi << 16);
}

// ---- packed-f16 selection primitives ----
__device__ __forceinline__ h2 max2(h2 a, h2 b) { return __builtin_elementwise_max(a, b); }
__device__ __forceinline__ h2 min2(h2 a, h2 b) { return __builtin_elementwise_min(a, b); }
__device__ __forceinline__ h2 cvt2(float lo, float hi) {
    return __builtin_bit_cast(h2, __builtin_amdgcn_cvt_pkrtz(lo, hi));
}
__device__ __forceinline__ void ce2(h2& hi, h2& lo) {
    const h2 m = max2(hi, lo);
    lo = min2(hi, lo);
    hi = m;
}
__device__ __forceinline__ void sort4_2(h2& a, h2& b, h2& c, h2& d) {
    ce2(a, b); ce2(c, d); ce2(a, c); ce2(b, d); ce2(b, c);
}
__device__ __forceinline__ void merge44_top5_2(h2 a0, h2 a1, h2 a2, h2 a3,
                                               h2 b0, h2 b1, h2 b2, h2 b3,
                                               h2& r0, h2& r1, h2& r2, h2& r3, h2& r4) {
    ce2(a0, b0); ce2(a2, b2); ce2(b0, a2);
    ce2(a1, b1); ce2(a3, b3); ce2(b1, a3);
    r0 = a0;
    r1 = a1; r2 = b0; ce2(r1, r2);
    r3 = b1; r4 = a2; ce2(r3, r4);
}
// r = top-5 of union of two descending sorted 5-lists (c_k = max_{i+j=k} min(a_i,b_j))
__device__ __forceinline__ void merge55_2(h2& r0, h2& r1, h2& r2, h2& r3, h2& r4,
                                          h2 s0, h2 s1, h2 s2, h2 s3, h2 s4) {
    const h2 m00 = min2(r0, s0);
    const h2 m10 = min2(r1, s0), m01 = min2(r0, s1);
    const h2 m20 = min2(r2, s0), m11 = min2(r1, s1), m02 = min2(r0, s2);
    const h2 m30 = min2(r3, s0), m21 = min2(r2, s1), m12 = min2(r1, s2), m03 = min2(r0, s3);
    const h2 n0 = max2(r0, s0);
    const h2 n1 = max2(max2(r1, s1), m00);
    const h2 n2 = max2(max2(r2, s2), max2(m10, m01));
    const h2 n3 = max2(max2(max2(r3, s3), m20), max2(m11, m02));
    const h2 n4 = max2(max2(max2(r4, s4), max2(m30, m03)), max2(m21, m12));
    r0 = n0; r1 = n1; r2 = n2; r3 = n3; r4 = n4;
}
// ---- scalar f32 helpers (epilogue only) ----
__device__ __forceinline__ void merge55f(float& r0, float& r1, float& r2, float& r3, float& r4,
                                         float s0, float s1, float s2, float s3, float s4) {
    const float m00 = fminf(r0, s0);
    const float m10 = fminf(r1, s0), m01 = fminf(r0, s1);
    const float m20 = fminf(r2, s0), m11 = fminf(r1, s1), m02 = fminf(r0, s2);
    const float m30 = fminf(r3, s0), m21 = fminf(r2, s1), m12 = fminf(r1, s2), m03 = fminf(r0, s3);
    const float n0 = fmaxf(r0, s0);
    const float n1 = fmaxf(fmaxf(r1, s1), m00);
    const float n2 = fmaxf(fmaxf(r2, s2), fmaxf(m10, m01));
    const float n3 = fmaxf(fmaxf(fmaxf(r3, s3), m20), fmaxf(m11, m02));
    const float n4 = fmaxf(fmaxf(fmaxf(r4, s4), fmaxf(m30, m03)), fmaxf(m21, m12));
    r0 = n0; r1 = n1; r2 = n2; r3 = n3; r4 = n4;
}
__device__ __forceinline__ void top5_insertf(float v, float& t0, float& t1,
                                             float& t2, float& t3, float& t4) {
    float b = fmaxf(t4, v);
    float m;
    m = fmaxf(t3, b);  b  = fminf(t3, b);  t3 = m;
    m = fmaxf(t2, t3); t3 = fminf(t2, t3); t2 = m;
    m = fmaxf(t1, t2); t2 = fminf(t1, t2); t1 = m;
    m = fmaxf(t0, t1); t1 = fminf(t0, t1); t0 = m;
    t4 = b;
}
// fold 32 acc values (two 32x32 accs, SAME column per lane) into running top-5
__device__ __forceinline__ void select32b(const f32x16& A0, const f32x16& A1, h2* rt) {
    h2 p[16];
    #pragma unroll
    for (int i = 0; i < 16; ++i) p[i] = cvt2(A0[i], A1[i]);
    sort4_2(p[0],  p[1],  p[2],  p[3]);
    sort4_2(p[4],  p[5],  p[6],  p[7]);
    sort4_2(p[8],  p[9],  p[10], p[11]);
    sort4_2(p[12], p[13], p[14], p[15]);
    h2 u0, u1, u2, u3, u4, v0, v1, v2, v3, v4;
    merge44_top5_2(p[0], p[1], p[2],  p[3],  p[4],  p[5],  p[6],  p[7],  u0, u1, u2, u3, u4);
    merge44_top5_2(p[8], p[9], p[10], p[11], p[12], p[13], p[14], p[15], v0, v1, v2, v3, v4);
    merge55_2(u0, u1, u2, u3, u4, v0, v1, v2, v3, v4);
    merge55_2(rt[0], rt[1], rt[2], rt[3], rt[4], u0, u1, u2, u3, u4);
}

// Single fused kernel: grid = B (256 blocks, 1/CU), 1024 threads (16 waves).
// 32x32x16 MFMA, single acc pair. STAGGERED tile walk: wave j=w&7 starts at
// position j of its tile ring and wraps — breaks the CU-wide phase-lock where
// all 16 waves hit the LDS pipe / matrix pipe / select VALU simultaneously
// (R12 counters: LDS 50k + MFMA 32k + VALU 29k cyc ≈ duration 111k — pipes
// were running back-to-back, not overlapped). Top-5 is order-independent.
__global__ __launch_bounds__(1024)
void shapelet_fused_kernel(const float* __restrict__ x,
                           const float* __restrict__ s,
                           float* __restrict__ out) {
    __shared__ __align__(16) unsigned short ldsS[K_SH * SSTR];   // 34816 B
    __shared__ __align__(16) unsigned short ldsX[8 * XSTR];      // 69760 B

    const int t    = threadIdx.x;
    const int lane = t & 63;
    const int w    = t >> 6;
    const int c7   = lane & 7;
    const int ub2  = (lane >> 3) & 3;
    const int q2   = lane >> 5;
    const int col  = lane & 31;
    const int g    = w >> 3;
    const int mp   = (w >> 2) & 1;
    const int kt   = w & 3;
    const int j8   = w & 7;           // stagger id within parity group
    const int b    = blockIdx.x;

    // ---- stage centered S as bf16: 8 threads per row k, 16 elems each ----
    {
        const int k = t >> 3, e8 = t & 7;
        const float4* srow = (const float4*)(s + k * L_SH + e8 * 16);
        float4 v[4];
        float sum = 0.0f;
        #pragma unroll
        for (int j = 0; j < 4; ++j) {
            v[j] = srow[j];
            sum += (v[j].x + v[j].y) + (v[j].z + v[j].w);
        }
        sum += __shfl_xor(sum, 1);
        sum += __shfl_xor(sum, 2);
        sum += __shfl_xor(sum, 4);
        const float mean = sum * (1.0f / 128.0f);
        uint4* dst = (uint4*)((char*)ldsS + k * (SSTR * 2) + e8 * 32);
        #pragma unroll
        for (int j = 0; j < 2; ++j) {
            uint4 o;
            o.x = pack2(f2bf(v[2*j].x - mean),   f2bf(v[2*j].y - mean));
            o.y = pack2(f2bf(v[2*j].z - mean),   f2bf(v[2*j].w - mean));
            o.z = pack2(f2bf(v[2*j+1].x - mean), f2bf(v[2*j+1].y - mean));
            o.w = pack2(f2bf(v[2*j+1].z - mean), f2bf(v[2*j+1].w - mean));
            dst[j] = o;
        }
        if (e8 == 7) *(uint4*)((char*)ldsS + k * (SSTR * 2) + 256) = make_uint4(0,0,0,0);
    }

    // ---- stage x row as 8 shifted bf16 copies; thread -> (copy = t&7, chunk) ----
    {
        const float* __restrict__ xb = x + (size_t)b * T_LEN;
        const int a = t & 7;
        for (int i = (t >> 3); i < XSTR / 8; i += 128) {
            const int p0 = 8 * i;
            float xv[16];
            if (p0 + 16 <= T_LEN) {
                const float4* sp = (const float4*)(xb + p0);
                #pragma unroll
                for (int j = 0; j < 4; ++j) *(float4*)(xv + 4 * j) = sp[j];
            } else {
                #pragma unroll
                for (int j = 0; j < 16; ++j) {
                    const int gi = p0 + j;
                    xv[j] = (gi < T_LEN) ? xb[gi] : 0.0f;
                }
            }
            unsigned short bv[16];
            #pragma unroll
            for (int j = 0; j < 16; ++j) bv[j] = f2bf(xv[j]);
            uint4 o;
            o.x = pack2(bv[a],     bv[a + 1]);
            o.y = pack2(bv[a + 2], bv[a + 3]);
            o.z = pack2(bv[a + 4], bv[a + 5]);
            o.w = pack2(bv[a + 6], bv[a + 7]);
            *(uint4*)((char*)ldsX + a * (XSTR * 2) + 2 * p0) = o;
        }
    }
    __syncthreads();

    // ---- hoist B fragments: wave's kt, 8 K-chunks of 16 ----
    bf16x8 bfr[8];
    #pragma unroll
    for (int c = 0; c < 8; ++c)
        bfr[c] = __builtin_bit_cast(bf16x8, *(const uint4*)(
            (const char*)ldsS + (32 * kt + col) * (SSTR * 2) + 32 * c + 16 * q2));

    // packed running top-5 (one column per lane)
    h2 rt[5];
    #pragma unroll
    for (int i = 0; i < 5; ++i) rt[i] = __builtin_bit_cast(h2, 0xFC00FC00u);

    // A-frag base: frag u of ring-position p at xp + p*512 + 32*u
    const char* xp = (const char*)ldsX + c7 * (XSTR * 2) + 16 * ub2 + 16 * q2
                   + 128 * mp + g * 256;

    f32x16 aA0, aA1;

#define LD(U) __builtin_bit_cast(bf16x8, *(const uint4*)(xq + 32 * (U)))
#define COMPUTE(X0, X1)                                                         \
    {                                                                           \
        _Pragma("unroll")                                                       \
        for (int i = 0; i < 16; ++i) { X0[i] = 0.f; X1[i] = 0.f; }              \
        bf16x8 f;                                                               \
        f = LD(0); X0 = __builtin_amdgcn_mfma_f32_32x32x16_bf16(f, bfr[0], X0, 0, 0, 0); \
        f = LD(1); X0 = __builtin_amdgcn_mfma_f32_32x32x16_bf16(f, bfr[1], X0, 0, 0, 0); \
        f = LD(2); X0 = __builtin_amdgcn_mfma_f32_32x32x16_bf16(f, bfr[2], X0, 0, 0, 0); \
                   X1 = __builtin_amdgcn_mfma_f32_32x32x16_bf16(f, bfr[0], X1, 0, 0, 0); \
        f = LD(3); X0 = __builtin_amdgcn_mfma_f32_32x32x16_bf16(f, bfr[3], X0, 0, 0, 0); \
                   X1 = __builtin_amdgcn_mfma_f32_32x32x16_bf16(f, bfr[1], X1, 0, 0, 0); \
        f = LD(4); X0 = __builtin_amdgcn_mfma_f32_32x32x16_bf16(f, bfr[4], X0, 0, 0, 0); \
                   X1 = __builtin_amdgcn_mfma_f32_32x32x16_bf16(f, bfr[2], X1, 0, 0, 0); \
        f = LD(5); X0 = __builtin_amdgcn_mfma_f32_32x32x16_bf16(f, bfr[5], X0, 0, 0, 0); \
                   X1 = __builtin_amdgcn_mfma_f32_32x32x16_bf16(f, bfr[3], X1, 0, 0, 0); \
        f = LD(6); X0 = __builtin_amdgcn_mfma_f32_32x32x16_bf16(f, bfr[6], X0, 0, 0, 0); \
                   X1 = __builtin_amdgcn_mfma_f32_32x32x16_bf16(f, bfr[4], X1, 0, 0, 0); \
        f = LD(7); X0 = __builtin_amdgcn_mfma_f32_32x32x16_bf16(f, bfr[7], X0, 0, 0, 0); \
                   X1 = __builtin_amdgcn_mfma_f32_32x32x16_bf16(f, bfr[5], X1, 0, 0, 0); \
        f = LD(8); X1 = __builtin_amdgcn_mfma_f32_32x32x16_bf16(f, bfr[6], X1, 0, 0, 0); \
        f = LD(9); X1 = __builtin_amdgcn_mfma_f32_32x32x16_bf16(f, bfr[7], X1, 0, 0, 0); \
    }

    // staggered ring walk: g=0 ring has 16 positions (tiles 0,2,..,30),
    // g=1 has 15 (tiles 1,3,..,29). Wave starts at position j8, wraps.
    {
        const int ns = (g == 0) ? 16 : 15;
        int pos = (j8 < ns) ? j8 : 0;
        for (int st = 0; st < ns; ++st) {
            const char* xq = xp + pos * 512;
            pos = (pos + 1 == ns) ? 0 : pos + 1;   // next address known early
            COMPUTE(aA0, aA1)
            select32b(aA0, aA1, rt);
        }
    }
#undef COMPUTE
#undef LD

    // ---- boundary row n = 3968 (element byte offset 7936), by (g=1, mp=0) ----
    f32x16 eb;
    if (g == 1 && mp == 0) {
        #pragma unroll
        for (int i = 0; i < 16; ++i) eb[i] = 0.f;
        const char* xq = (const char*)ldsX + c7 * (XSTR * 2) + 16 * ub2 + 16 * q2 + 7936;
        #pragma unroll
        for (int c = 0; c < 8; ++c) {
            const bf16x8 f = __builtin_bit_cast(bf16x8, *(const uint4*)(xq + 32 * c));
            eb = __builtin_amdgcn_mfma_f32_32x32x16_bf16(f, bfr[c], eb, 0, 0, 0);
        }
    }

    // ---- epilogue: unpack both row-groups of the column list and merge ----
    float a0 = (float)rt[0][0], a1 = (float)rt[1][0], a2 = (float)rt[2][0],
          a3 = (float)rt[3][0], a4 = (float)rt[4][0];
    merge55f(a0, a1, a2, a3, a4,
             (float)rt[0][1], (float)rt[1][1], (float)rt[2][1],
             (float)rt[3][1], (float)rt[4][1]);

    // boundary insert: eb reg0 row = 4*q2 -> n=3968 valid only for q2==0 lanes
    if (g == 1 && mp == 0) {
        const float v = (q2 == 0) ? eb[0] : NEG_INF;
        top5_insertf(v, a0, a1, a2, a3, a4);
    }

    // merge the two q2 halves of each column (snapshot BEFORE merging)
    {
        const float s0 = __shfl_xor(a0, 32), s1 = __shfl_xor(a1, 32),
                    s2 = __shfl_xor(a2, 32), s3 = __shfl_xor(a3, 32),
                    s4 = __shfl_xor(a4, 32);
        merge55f(a0, a1, a2, a3, a4, s0, s1, s2, s3, s4);
    }

    // ---- cross-(g, mp) merge via LDS: slots 1..3 write, slot 0 reads ----
    __syncthreads();   // every wave past its bfr hoist & tile loop; ldsS reusable
    float* sc = (float*)ldsS;          // [slot-1][128 cols][5]
    const int slot = 2 * g + mp;
    if (slot != 0 && lane < 32) {
        float* p = sc + (((slot - 1) * 128) + kt * 32 + col) * 5;
        p[0] = a0; p[1] = a1; p[2] = a2; p[3] = a3; p[4] = a4;
    }
    __syncthreads();
    if (slot == 0 && lane < 32) {
        #pragma unroll
        for (int sreg = 0; sreg < 3; ++sreg) {
            const float* p = sc + ((sreg * 128) + kt * 32 + col) * 5;
            merge55f(a0, a1, a2, a3, a4, p[0], p[1], p[2], p[3], p[4]);
        }
        const int ks = 32 * kt + col;
        float* ob = out + (size_t)b * (4 * K_SH);
        const float pmean = (((a0 + a1) + (a2 + a3)) + a4) * 0.2f;
        ob[ks]            = a0;
        ob[K_SH + ks]     = pmean;
        ob[2*K_SH + ks]   = a1;
        ob[3*K_SH + ks]   = fmaxf(a0 - a1, 0.0f);
    }
}

extern "C" void kernel_launch(void* const* d_in, const int* in_sizes, int n_in,
                              void* d_out, int out_size, void* d_ws, size_t ws_size,
                              hipStream_t stream) {
    const float* x = (const float*)d_in[0];        // (256, 4096) fp32
    const float* s = (const float*)d_in[1];        // (128, 128)  fp32
    float* out = (float*)d_out;                    // (256, 512)  fp32
    shapelet_fused_kernel<<<B_SZ, 1024, 0, stream>>>(x, s, out);
}